// Round 1
// 627.271 us; speedup vs baseline: 1.0077x; 1.0077x over previous
//
#include <hip/hip_runtime.h>
#include <hip/hip_bf16.h>

static constexpr float kLog2 = 0.6931471805599453f;

__device__ __forceinline__ float sspf(float x) {
    return fmaxf(x, 0.0f) + __logf(1.0f + __expf(-fabsf(x))) - kLog2;
}

typedef __attribute__((ext_vector_type(8))) _Float16 half8;
typedef __attribute__((ext_vector_type(4))) _Float16 half4v;
typedef __attribute__((ext_vector_type(4))) float float4v;

// ---------------- dense GEMMs (f16 MFMA 16x16x32, whole K in LDS) ----------
template <bool ACT, typename OUT>
__device__ __forceinline__ void gemm_mfma_body(const float* __restrict__ A,
                                               const float* __restrict__ B,
                                               const float* __restrict__ bias,
                                               OUT* __restrict__ C, int M,
                                               int blockid) {
    constexpr int LDH = 136;
    __shared__ _Float16 Als[64 * LDH];
    __shared__ _Float16 Bls[128 * LDH];
    const int tid = threadIdx.x;
    const int rowbase = blockid * 64;
#pragma unroll
    for (int j = 0; j < 8; ++j) {
        int idx = j * 256 + tid;
        int r = idx >> 5, c4 = (idx & 31) << 2;
        int rg = rowbase + r;
        rg = rg < M ? rg : (M - 1);
        float4 v = *(const float4*)(A + (size_t)rg * 128 + c4);
        half4v hv = {(_Float16)v.x, (_Float16)v.y, (_Float16)v.z, (_Float16)v.w};
        *(half4v*)&Als[r * LDH + c4] = hv;
    }
#pragma unroll
    for (int j = 0; j < 16; ++j) {
        int idx = j * 256 + tid;
        int r = idx >> 5, c4 = (idx & 31) << 2;
        float4 v = *(const float4*)(B + (size_t)r * 128 + c4);
        half4v hv = {(_Float16)v.x, (_Float16)v.y, (_Float16)v.z, (_Float16)v.w};
        *(half4v*)&Bls[r * LDH + c4] = hv;
    }
    __syncthreads();

    const int wave = tid >> 6, lane = tid & 63;
    const int l15 = lane & 15, q = lane >> 4;
    float4v acc[8];
#pragma unroll
    for (int nt = 0; nt < 8; ++nt) acc[nt] = (float4v){0.f, 0.f, 0.f, 0.f};
    const int am = wave * 16 + l15;
#pragma unroll
    for (int kk = 0; kk < 4; ++kk) {
        half8 af = *(const half8*)&Als[am * LDH + kk * 32 + q * 8];
#pragma unroll
        for (int nt = 0; nt < 8; ++nt) {
            half8 bfv = *(const half8*)&Bls[(nt * 16 + l15) * LDH + kk * 32 + q * 8];
            acc[nt] = __builtin_amdgcn_mfma_f32_16x16x32_f16(af, bfv, acc[nt], 0, 0, 0);
        }
    }
#pragma unroll
    for (int nt = 0; nt < 8; ++nt) {
        int n = nt * 16 + l15;
        float bv = bias[n];
#pragma unroll
        for (int r = 0; r < 4; ++r) {
            int m = rowbase + wave * 16 + q * 4 + r;
            if (m < M) {
                float v = acc[nt][r] + bv;
                if (ACT) v = sspf(v);
                C[(size_t)m * 128 + n] = (OUT)v;
            }
        }
    }
}

__global__ __launch_bounds__(256) void gemm_in_count_kernel(
    const float* __restrict__ A, const float* __restrict__ B,
    const float* __restrict__ bias, _Float16* __restrict__ C, int M,
    const int* __restrict__ idx_i, int* __restrict__ counts, int P,
    int gemm_blocks) {
    if ((int)blockIdx.x < gemm_blocks) {
        gemm_mfma_body<false, _Float16>(A, B, bias, C, M, blockIdx.x);
    } else {
        const int nthr = (gridDim.x - gemm_blocks) * 256;
        for (int p = (blockIdx.x - gemm_blocks) * 256 + threadIdx.x; p < P;
             p += nthr)
            atomicAdd(&counts[idx_i[p]], 1);
    }
}

__global__ __launch_bounds__(256) void gemm_out_kernel(
    const float* __restrict__ A, const float* __restrict__ B,
    const float* __restrict__ bias, float* __restrict__ C, int M) {
    gemm_mfma_body<true, float>(A, B, bias, C, M, blockIdx.x);
}

// ---- one-kernel segment allocation: block scan + global bump (order-free) ----
__global__ __launch_bounds__(256) void alloc_starts_kernel(
    const int* __restrict__ counts, int* __restrict__ starts,
    int* __restrict__ cursor, int* __restrict__ gtot, int N) {
    __shared__ int s[256];
    __shared__ int base;
    const int t = threadIdx.x, g = blockIdx.x * 256 + t;
    const int c = g < N ? counts[g] : 0;
    s[t] = c;
    __syncthreads();
    for (int o = 1; o < 256; o <<= 1) {
        int v = t >= o ? s[t - o] : 0;
        __syncthreads();
        s[t] += v;
        __syncthreads();
    }
    if (t == 255) base = atomicAdd(gtot, s[255]);
    __syncthreads();
    const int excl = base + s[t] - c;
    if (g < N) {
        starts[g] = excl;
        cursor[g] = excl;
    }
}

// ---- fill: scatter edge payload into segment-sorted order ----
// EF path: ef[pos] = 24 f16 {f_ij[0..19], 1.0(bias mult), 0,0,0}; meta = {jb, rc}.
// fallback: pidx[pos] = p (gather re-reads f_ij f32 via indirection).
template <bool EF>
__global__ __launch_bounds__(256) void fill_kernel(
    const int* __restrict__ idx_i, const int* __restrict__ idx_j,
    const float* __restrict__ rcut, const float* __restrict__ f_ij,
    int* __restrict__ cursor, _Float16* __restrict__ ef,
    int2* __restrict__ meta, int* __restrict__ pidx, int P) {
    int p = blockIdx.x * 256 + threadIdx.x;
    if (p >= P) return;
    const int i = idx_i[p];
    const int pos = atomicAdd(&cursor[i], 1);
    meta[pos] = make_int2(idx_j[p] << 7, __float_as_int(rcut[p]));
    if (EF) {
        const float* fr = f_ij + (size_t)p * 20;
        _Float16 hb[24];
#pragma unroll
        for (int r = 0; r < 20; r += 4) {
            float4 v = *(const float4*)(fr + r);
            hb[r] = (_Float16)v.x; hb[r + 1] = (_Float16)v.y;
            hb[r + 2] = (_Float16)v.z; hb[r + 3] = (_Float16)v.w;
        }
        hb[20] = (_Float16)1.0f; hb[21] = (_Float16)0.0f;
        hb[22] = (_Float16)0.0f; hb[23] = (_Float16)0.0f;
        _Float16* dst = ef + (size_t)pos * 24;
        *(half8*)dst = *(half8*)hb;
        *(half8*)(dst + 8) = *(half8*)(hb + 8);
        *(half8*)(dst + 16) = *(half8*)(hb + 16);
    } else {
        pidx[pos] = p;
    }
}

// ---- gather: TWO waves per atom (64 features each), 16 edges/MFMA group.
//      3-stage pipeline: meta/ef prefetched 2 chunks ahead, h-row gather (hv)
//      prefetched 1 chunk ahead so its ~200-400cy L2 latency hides under the
//      previous chunk's MFMA+sspf work. ----
template <bool EF>
__global__ __launch_bounds__(256, 4) void gather_mfma_kernel(
    const _Float16* __restrict__ ef, const int2* __restrict__ meta,
    const int* __restrict__ pidx, const float* __restrict__ f_ij,
    const float* __restrict__ Wf, const float* __restrict__ bf,
    const _Float16* __restrict__ h16, const int* __restrict__ starts,
    const int* __restrict__ counts, float* __restrict__ agg, int N) {
    const int lane = threadIdx.x & 63;
    const int gwave = (blockIdx.x * 256 + threadIdx.x) >> 6;
    const int nwaves = (gridDim.x * 256) >> 6;
    const int l15 = lane & 15, q = lane >> 4;
    const int fh = gwave & 1;       // feature half: tiles [fh*4, fh*4+4)
    const int fbase = fh * 64;      // feature offset of this wave

    // A-fragments: W_filter rows for this wave's 4 tiles, bias at k=20.
    half8 wfr[4];
#pragma unroll
    for (int t = 0; t < 4; ++t) {
        const int n = fbase + t * 16 + l15;
        const float* wr = Wf + (size_t)n * 20;
        float v[8];
#pragma unroll
        for (int j = 0; j < 8; ++j) {
            int k = q * 8 + j;
            v[j] = (k < 20) ? wr[k] : ((k == 20) ? bf[n] : 0.0f);
        }
        wfr[t] = (half8){(_Float16)v[0], (_Float16)v[1], (_Float16)v[2],
                         (_Float16)v[3], (_Float16)v[4], (_Float16)v[5],
                         (_Float16)v[6], (_Float16)v[7]};
    }
    const float4v zero = {0.f, 0.f, 0.f, 0.f};
    const _Float16* hbase = h16 + fbase + q * 4;  // + jb + t*16 per access

    // unit u = (atom i) * 2 + feature-half; nwaves is even so fh is fixed.
    for (int u = gwave; u < 2 * N; u += nwaves) {
        const int i = u >> 1;
        const int s = __builtin_amdgcn_readfirstlane(starts[i]);
        const int cnt = __builtin_amdgcn_readfirstlane(counts[i]);
        const int e = s + cnt;
        float4v acc[4];
#pragma unroll
        for (int t = 0; t < 4; ++t) acc[t] = zero;

        if (cnt > 0) {
            // stage: chunk0 meta/ef
            int pos0 = min(s + l15, e - 1);
            int2 mt_c = meta[pos0];
            half8 bf_c = {};
            int p_c = 0;
            if (EF) {
                if (q < 3) bf_c = *(const half8*)(ef + (size_t)pos0 * 24 + q * 8);
            } else {
                p_c = pidx[pos0];
            }
            // stage: chunk1 meta/ef
            int2 mt_n = mt_c;
            half8 bf_n = bf_c;
            int p_n = p_c;
            if (s + 16 < e) {
                int pos1 = min(s + 16 + l15, e - 1);
                mt_n = meta[pos1];
                if (EF) {
                    if (q < 3) bf_n = *(const half8*)(ef + (size_t)pos1 * 24 + q * 8);
                } else {
                    p_n = pidx[pos1];
                }
            }
            // stage: chunk0 h-rows (one meta-latency stall, once per unit)
            half4v hv_c[4];
            {
                const _Float16* hp = hbase + mt_c.x;
#pragma unroll
                for (int t = 0; t < 4; ++t) hv_c[t] = *(const half4v*)(hp + t * 16);
            }

            for (int c = s; c < e; c += 16) {
                // issue next chunk's h-row gather (mt_n arrived a chunk ago)
                half4v hv_n[4];
                if (c + 16 < e) {
                    const _Float16* hp = hbase + mt_n.x;
#pragma unroll
                    for (int t = 0; t < 4; ++t) hv_n[t] = *(const half4v*)(hp + t * 16);
                }
                // prefetch meta/ef two chunks ahead
                int2 mt_n2 = mt_n;
                half8 bf_n2 = bf_n;
                int p_n2 = p_n;
                if (c + 32 < e) {
                    int pos2 = min(c + 32 + l15, e - 1);
                    mt_n2 = meta[pos2];
                    if (EF) {
                        if (q < 3) bf_n2 = *(const half8*)(ef + (size_t)pos2 * 24 + q * 8);
                    } else {
                        p_n2 = pidx[pos2];
                    }
                }
                if (!EF) {  // build B-fragment from f32 f_ij (fallback)
                    const float* fp = f_ij + (size_t)p_c * 20;
                    float b0 = 0.f, b1 = 0.f, b2 = 0.f, b3 = 0.f;
                    float b4 = 0.f, b5 = 0.f, b6 = 0.f, b7 = 0.f;
                    if (q <= 2) {
                        float4 a = *(const float4*)(fp + q * 8);
                        b0 = a.x; b1 = a.y; b2 = a.z; b3 = a.w;
                    }
                    if (q <= 1) {
                        float4 bb = *(const float4*)(fp + q * 8 + 4);
                        b4 = bb.x; b5 = bb.y; b6 = bb.z; b7 = bb.w;
                    }
                    if (q == 2) b4 = 1.0f;
                    bf_c = (half8){(_Float16)b0, (_Float16)b1, (_Float16)b2,
                                   (_Float16)b3, (_Float16)b4, (_Float16)b5,
                                   (_Float16)b6, (_Float16)b7};
                }
                const float rc = (c + l15 < e) ? __int_as_float(mt_c.y) : 0.0f;
#pragma unroll
                for (int t = 0; t < 4; ++t) {
                    float4v d = __builtin_amdgcn_mfma_f32_16x16x32_f16(
                        wfr[t], bf_c, zero, 0, 0, 0);
#pragma unroll
                    for (int r = 0; r < 4; ++r) {
                        float w = sspf(d[r]) * rc;
                        acc[t][r] = fmaf(w, (float)hv_c[t][r], acc[t][r]);
                    }
                }
                // rotate pipeline registers
                mt_c = mt_n; mt_n = mt_n2;
                bf_c = bf_n; bf_n = bf_n2;
                p_c = p_n;   p_n = p_n2;
#pragma unroll
                for (int t = 0; t < 4; ++t) hv_c[t] = hv_n[t];
            }
        }
        // reduce across the 16-edge (l15) dimension
#pragma unroll
        for (int m = 1; m <= 8; m <<= 1)
#pragma unroll
            for (int t = 0; t < 4; ++t)
#pragma unroll
                for (int r = 0; r < 4; ++r)
                    acc[t][r] += __shfl_xor(acc[t][r], m, 64);
        if (l15 == 0) {
#pragma unroll
            for (int t = 0; t < 4; ++t) {
                float4 o = {acc[t][0], acc[t][1], acc[t][2], acc[t][3]};
                *(float4*)(agg + (size_t)i * 128 + fbase + t * 16 + q * 4) = o;
            }
        }
    }
}

extern "C" void kernel_launch(void* const* d_in, const int* in_sizes, int n_in,
                              void* d_out, int out_size, void* d_ws, size_t ws_size,
                              hipStream_t stream) {
    const float* x     = (const float*)d_in[0];
    const float* f_ij  = (const float*)d_in[1];
    const int*   idx_i = (const int*)d_in[2];
    const int*   idx_j = (const int*)d_in[3];
    const float* rcut  = (const float*)d_in[4];
    const float* W_in  = (const float*)d_in[5];
    const float* b_in  = (const float*)d_in[6];
    const float* W_f   = (const float*)d_in[7];
    const float* b_f   = (const float*)d_in[8];
    const float* W_out = (const float*)d_in[9];
    const float* b_out = (const float*)d_in[10];

    const int N = in_sizes[0] / 128;  // 50000
    const int P = in_sizes[2];        // 1600000

    // workspace layout (16B-aligned chunks)
    char* ws = (char*)d_ws;
    size_t off = 0;
    auto alloc = [&](size_t bytes) {
        void* ptr = ws + off;
        off += (bytes + 15) & ~(size_t)15;
        return ptr;
    };
    int* counts  = (int*)alloc((size_t)N * 4 + 16);  // gtot rides at counts[N..]
    int* gtot    = counts + N;
    int* starts  = (int*)alloc((size_t)N * 4);
    int* cursor  = (int*)alloc((size_t)N * 4);
    _Float16* h16 = (_Float16*)alloc((size_t)N * 128 * 2);
    int2* meta   = (int2*)alloc((size_t)P * 8);
    size_t base_need = off;
    const bool use_ef = (base_need + (size_t)P * 24 * 2 + 64) <= ws_size;
    _Float16* ef = nullptr;
    int* pidx = nullptr;
    if (use_ef) ef = (_Float16*)alloc((size_t)P * 24 * 2 + 64);
    else        pidx = (int*)alloc((size_t)P * 4);

    float* agg = (float*)d_out;  // gather writes agg; gemm_out runs in-place

    const int mblocks = (N + 63) / 64;  // 782
    const int cblocks = 768;
    const int NB = (N + 255) / 256;

    hipMemsetAsync(counts, 0, (size_t)N * 4 + 16, stream);  // counts + gtot
    gemm_in_count_kernel<<<mblocks + cblocks, 256, 0, stream>>>(
        x, W_in, b_in, h16, N, idx_i, counts, P, mblocks);
    alloc_starts_kernel<<<NB, 256, 0, stream>>>(counts, starts, cursor, gtot, N);
    if (use_ef) {
        fill_kernel<true><<<(P + 255) / 256, 256, 0, stream>>>(
            idx_i, idx_j, rcut, f_ij, cursor, ef, meta, pidx, P);
        gather_mfma_kernel<true><<<4096, 256, 0, stream>>>(
            ef, meta, pidx, f_ij, W_f, b_f, h16, starts, counts, agg, N);
    } else {
        fill_kernel<false><<<(P + 255) / 256, 256, 0, stream>>>(
            idx_i, idx_j, rcut, f_ij, cursor, ef, meta, pidx, P);
        gather_mfma_kernel<false><<<4096, 256, 0, stream>>>(
            ef, meta, pidx, f_ij, W_f, b_f, h16, starts, counts, agg, N);
    }
    gemm_out_kernel<<<mblocks, 256, 0, stream>>>(agg, W_out, b_out, (float*)d_out, N);
}